// Round 9
// baseline (449.471 us; speedup 1.0000x reference)
//
#include <hip/hip_runtime.h>
#include <hip/hip_bf16.h>

// LRRNN: B=64, dz=16, K=16, N=1024, dx=128, T=500 (T read from input 8).
// 64 blocks, 8 waves x 128 N-rows. Phase A batched for ILP (8 indep X-MFMAs
// -> relu/pack -> 4x mfma 16x16x32, k-permutation-invariant packing).
// NO s_barrier in the main loop: point-to-point LDS flag sync.
//   waves: write partial -> lgkmcnt(0) -> pflag[w]=t+1
//   wave0: poll 8 pflags -> read 7 partials -> z update -> zbuf -> lgkmcnt(0)
//          -> zflag[lane]=t+1
//   readers: poll zflag[lane] -> read zbuf. They wait only on wave0, never on
//   each other; global readout stores are NEVER drained (no barrier -> no
//   vmcnt(0) in the loop). Monotonic flags make single-buffered partials
//   race-free (wave0's reads precede its zflag write; peers' next writes are
//   gated on zflag). Readout batched every CH steps from a register ring.

typedef __attribute__((ext_vector_type(4))) short short4v;
typedef __attribute__((ext_vector_type(8))) short short8v;
typedef __attribute__((ext_vector_type(4))) float float4v;

#define BB 64
#define DZ 16
#define KC 16
#define NN 1024
#define DX 128
#define NW 8                    // waves per block (== DX/16 readout tiles)
#define ITER (NN / (16 * NW))   // 8 row-tiles per wave
#define NH (ITER / 2)           // 4 x32 n-MFMAs per wave
#define CH 8                    // steps per readout chunk (register ring depth)

union FragAB {
  short4v s;
  __hip_bfloat162 h2[2];
};
union Frag8 {
  short8v s8;
  short4v s4[2];
};

__device__ inline short4v pack_bf16x4(float a, float b, float c, float d) {
  FragAB u;
  u.h2[0] = __float22bfloat162_rn(make_float2(a, b));
  u.h2[1] = __float22bfloat162_rn(make_float2(c, d));
  return u.s;
}

// every branch __has_builtin-guarded: the HOST pass has none of these builtins
// and must fall through to the (never-executed) asm string.
__device__ inline float4v mfma_bf16(short4v a, short4v b, float4v c) {
#if __has_builtin(__builtin_amdgcn_mfma_f32_16x16x16bf16_1k)
  return __builtin_amdgcn_mfma_f32_16x16x16bf16_1k(a, b, c, 0, 0, 0);
#elif __has_builtin(__builtin_amdgcn_mfma_f32_16x16x16_bf16)
  return __builtin_amdgcn_mfma_f32_16x16x16_bf16(a, b, c, 0, 0, 0);
#else
  float4v d;
  asm("v_mfma_f32_16x16x16_bf16 %0, %1, %2, %3"
      : "=v"(d) : "v"(a), "v"(b), "v"(c));
  return d;
#endif
}

__device__ inline float4v mfma_bf16_x32(short8v a, short8v b, float4v c) {
#if __has_builtin(__builtin_amdgcn_mfma_f32_16x16x32_bf16)
  return __builtin_amdgcn_mfma_f32_16x16x32_bf16(a, b, c, 0, 0, 0);
#else
  float4v d;
  asm("v_mfma_f32_16x16x32_bf16 %0, %1, %2, %3"
      : "=v"(d) : "v"(a), "v"(b), "v"(c));
  return d;
#endif
}

__global__ __launch_bounds__(64 * NW, 2)
void lrrnn_fused(const float* __restrict__ z0, const float* __restrict__ Adec,
                 const float* __restrict__ nmat, const float* __restrict__ mmat,
                 const float* __restrict__ hvec, const float* __restrict__ hzvec,
                 const float* __restrict__ Bobs, const float* __restrict__ Bias,
                 const int* __restrict__ Tptr, float* __restrict__ out)
{
  const int T    = Tptr[0];
  const int b    = blockIdx.x;
  const int tid  = threadIdx.x;
  const int wave = tid >> 6;
  const int lane = tid & 63;
  const int g    = lane >> 4;   // 0..3  (quad group)
  const int c    = lane & 15;   // 0..15 (column / row-in-tile)

  __shared__ float4v part[NW][64];       // per-wave partials (single-buffered;
                                         // safe via monotonic flag protocol)
  __shared__ short4v zbuf[64];           // packed bf16 z broadcast (8 B/lane)
  __shared__ unsigned zflag[64];         // per-lane publish counter for zbuf
  __shared__ unsigned short pflags[8];   // per-wave partial-publish counters

  // one-time flag init (the ONLY barrier in the kernel)
  if (tid < 64) zflag[tid] = 0u;
  if (tid < 8)  pflags[tid] = 0;
  __syncthreads();

  // ---- one-time fragment preload (weights shared across blocks; L2-resident) ----
  // m A-frag (x16): A[row=c][k=4g+j] = m[(rowbase+c)*16 + 4g+j]
  // n A-frag (x32): slot j<4 -> n[c*1024 + rb+4g+j], j>=4 -> n[c*1024 + rb+16+4g+j-4]
  // negH C-frag: C[row=4g+r][col] = -h[rowbase + 4g+r]
  FragAB mf[ITER];
  Frag8  nf8[NH];
  float4v negH[ITER];
#pragma unroll
  for (int i = 0; i < ITER; ++i) {
    const int rowbase = wave * (16 * ITER) + i * 16;
    float4v mv = *(const float4v*)(mmat + (rowbase + c) * DZ + g * 4);
    mf[i].s = pack_bf16x4(mv[0], mv[1], mv[2], mv[3]);
    float4v hv = *(const float4v*)(hvec + rowbase + g * 4);
    negH[i][0] = -hv[0]; negH[i][1] = -hv[1];
    negH[i][2] = -hv[2]; negH[i][3] = -hv[3];
  }
#pragma unroll
  for (int i = 0; i < NH; ++i) {
    const int rb0 = wave * (16 * ITER) + (2 * i) * 16;
    float4v nv0 = *(const float4v*)(nmat + c * NN + rb0 + g * 4);
    float4v nv1 = *(const float4v*)(nmat + c * NN + rb0 + 16 + g * 4);
    nf8[i].s4[0] = pack_bf16x4(nv0[0], nv0[1], nv0[2], nv0[3]);
    nf8[i].s4[1] = pack_bf16x4(nv1[0], nv1[1], nv1[2], nv1[3]);
  }

  // decay / bias-z frags (C-layout rows = z = 4g+r); wave0 is the z owner
  const float4v Af  = *(const float4v*)(Adec + g * 4);
  const float4v hzf = *(const float4v*)(hzvec + g * 4);
  const float4v zerov = {0.f, 0.f, 0.f, 0.f};

  // ---- readout: wave w owns x-tile w (x in [16w, 16w+16)), NW==DX/16 ----
  // BobsT A-frag: A[row=x=c][k=z=4g+j] = Bobs[(4g+j)*128 + x]
  FragAB bobsF;
  float4v biasF;
  unsigned oof[4];
  {
    const int xb = wave * 16;
    bobsF.s = pack_bf16x4(Bobs[(4 * g + 0) * DX + xb + c],
                          Bobs[(4 * g + 1) * DX + xb + c],
                          Bobs[(4 * g + 2) * DX + xb + c],
                          Bobs[(4 * g + 3) * DX + xb + c]);
    biasF = *(const float4v*)(Bias + xb + g * 4);
#pragma unroll
    for (int rr = 0; rr < 4; ++rr) {
      const int x = xb + g * 4 + rr;
      oof[rr] = (unsigned)(b * DX + x) * (unsigned)T * KC + c;
    }
  }

  // z state: f32 master in wave0 only; all waves track packed bf16 zb
  float4v zf;
#pragma unroll
  for (int j = 0; j < 4; ++j)
    zf[j] = z0[b * DZ * KC + (g * 4 + j) * KC + c];
  FragAB zb;
  zb.s = pack_bf16x4(zf[0], zf[1], zf[2], zf[3]);

  // one recurrence step for absolute step index t. Updates zb (all waves).
  auto do_step = [&](int t) {
    const unsigned want = (unsigned)t + 1u;

    // ---- phase A (R6-proven): 8 indep X-MFMAs -> relu/pack -> 4x x32 ----
    float4v xv[ITER];
#pragma unroll
    for (int i = 0; i < ITER; ++i)
      xv[i] = mfma_bf16(mf[i].s, zb.s, negH[i]);

    Frag8 R8[NH];
#pragma unroll
    for (int i = 0; i < NH; ++i) {
      const float4v x0 = xv[2 * i], x1 = xv[2 * i + 1];
      R8[i].s4[0] = pack_bf16x4(fmaxf(x0[0], 0.f), fmaxf(x0[1], 0.f),
                                fmaxf(x0[2], 0.f), fmaxf(x0[3], 0.f));
      R8[i].s4[1] = pack_bf16x4(fmaxf(x1[0], 0.f), fmaxf(x1[1], 0.f),
                                fmaxf(x1[2], 0.f), fmaxf(x1[3], 0.f));
    }

    float4v a0 = mfma_bf16_x32(nf8[0].s8, R8[0].s8, (wave == 0) ? hzf : zerov);
    float4v a1 = mfma_bf16_x32(nf8[1].s8, R8[1].s8, zerov);
    a0 = mfma_bf16_x32(nf8[2].s8, R8[2].s8, a0);
    a1 = mfma_bf16_x32(nf8[3].s8, R8[3].s8, a1);
    const float4v zp = a0 + a1;

    if (wave != 0) {
      // ---- publish partial: data -> lgkmcnt(0) -> flag ----
      part[wave][lane] = zp;
      asm volatile("s_waitcnt lgkmcnt(0)" ::: "memory");
      if (lane == 0)
        ((volatile unsigned short*)pflags)[wave] = (unsigned short)want;

      // ---- wait for wave0's z publish (only dependency: wave0) ----
      while (((const volatile unsigned*)zflag)[lane] != want) {}
      asm volatile("" ::: "memory");   // force zbuf re-load after the loop
      zb.s = zbuf[lane];
    } else {
      // ---- wave0: gather partials as they land ----
      if (lane == 0)
        ((volatile unsigned short*)pflags)[0] = (unsigned short)want;
      const unsigned want2 = (want & 0xffffu) | (want << 16);
      const volatile unsigned* pf = (const volatile unsigned*)pflags;
      for (;;) {
        const unsigned f0 = pf[0], f1 = pf[1], f2 = pf[2], f3 = pf[3];
        if (f0 == want2 && f1 == want2 && f2 == want2 && f3 == want2) break;
      }
      asm volatile("" ::: "memory");   // force partial re-loads after the loop
      const float4v p1 = part[1][lane];
      const float4v p2 = part[2][lane];
      const float4v p3 = part[3][lane];
      const float4v p4 = part[4][lane];
      const float4v p5 = part[5][lane];
      const float4v p6 = part[6][lane];
      const float4v p7 = part[7][lane];
      const float4v tot = ((zp + p1) + (p2 + p3)) + ((p4 + p5) + (p6 + p7));
#pragma unroll
      for (int j = 0; j < 4; ++j)
        zf[j] = fmaf(Af[j], zf[j], tot[j]);
      zb.s = pack_bf16x4(zf[0], zf[1], zf[2], zf[3]);
      // ---- publish z: data -> lgkmcnt(0) -> per-lane flag ----
      zbuf[lane] = zb.s;
      asm volatile("s_waitcnt lgkmcnt(0)" ::: "memory");
      ((volatile unsigned*)zflag)[lane] = want;
    }
  };

  int t = 0;
  // ---- main: chunks of CH steps, readout batched from the register ring ----
  while (t + CH <= T) {
    short4v hist[CH];                 // compile-time-indexed -> stays in VGPRs
#pragma unroll
    for (int s = 0; s < CH; ++s) {
      do_step(t + s);
      hist[s] = zb.s;                 // zb = z_{t+s+1} -> out index t+s
    }
#pragma unroll
    for (int s = 0; s < CH; ++s) {
      float4v o = mfma_bf16(bobsF.s, hist[s], biasF);
      const unsigned tk = (unsigned)(t + s) * KC;
#pragma unroll
      for (int rr = 0; rr < 4; ++rr)
        out[oof[rr] + tk] = o[rr];
    }
    t += CH;
  }
  // ---- tail: per-step immediate readout (<=CH-1 steps) ----
  for (; t < T; ++t) {
    do_step(t);
    float4v o = mfma_bf16(bobsF.s, zb.s, biasF);
    const unsigned tk = (unsigned)t * KC;
#pragma unroll
    for (int rr = 0; rr < 4; ++rr)
      out[oof[rr] + tk] = o[rr];
  }
}

extern "C" void kernel_launch(void* const* d_in, const int* in_sizes, int n_in,
                              void* d_out, int out_size, void* d_ws, size_t ws_size,
                              hipStream_t stream) {
  const float* z0   = (const float*)d_in[0];
  const float* A    = (const float*)d_in[1];
  const float* nmat = (const float*)d_in[2];
  const float* mmat = (const float*)d_in[3];
  const float* h    = (const float*)d_in[4];
  const float* hz   = (const float*)d_in[5];
  const float* Bobs = (const float*)d_in[6];
  const float* Bias = (const float*)d_in[7];
  const int*   T    = (const int*)d_in[8];
  (void)in_sizes; (void)n_in; (void)out_size; (void)d_ws; (void)ws_size;
  lrrnn_fused<<<dim3(BB), dim3(64 * NW), 0, stream>>>(
      z0, A, nmat, mmat, h, hz, Bobs, Bias, T, (float*)d_out);
}

// Round 10
// 342.843 us; speedup vs baseline: 1.3110x; 1.3110x over previous
//
#include <hip/hip_runtime.h>
#include <hip/hip_bf16.h>

// LRRNN: B=64, dz=16, K=16, N=1024, dx=128, T=500 (T read from input 8).
// 64 blocks, 8 waves x 128 N-rows. Phase A batched for ILP (8 indep X-MFMAs
// -> relu/pack -> 4x mfma 16x16x32, k-permutation-invariant packing).
// R6 sync structure (best measured): partials -> rendezvous -> wave0 reduce +
// z update + packed-bf16 zbuf broadcast -> rendezvous -> 8B zbuf read.
// KEY CHANGE vs R6: raw `s_waitcnt lgkmcnt(0); s_barrier` instead of
// __syncthreads() -- __syncthreads forces s_waitcnt vmcnt(0) before the
// barrier, draining the chunk's 32 global readout stores (~500-900 cyc once
// per chunk) on the whole block's critical path. LDS correctness only needs
// lgkmcnt. Stores now retire lazily under later compute (T4: never drain
// vmcnt in the loop). Readout batched every CH=16 steps from a register ring.

typedef __attribute__((ext_vector_type(4))) short short4v;
typedef __attribute__((ext_vector_type(8))) short short8v;
typedef __attribute__((ext_vector_type(4))) float float4v;

#define BB 64
#define DZ 16
#define KC 16
#define NN 1024
#define DX 128
#define NW 8                    // waves per block (== DX/16 readout tiles)
#define ITER (NN / (16 * NW))   // 8 row-tiles per wave
#define NH (ITER / 2)           // 4 x32 n-MFMAs per wave
#define CH 16                   // steps per readout chunk (register ring depth)

// execution barrier + LDS publish; NO vmcnt drain (that's the whole point)
#define BARRIER_LGKM() asm volatile("s_waitcnt lgkmcnt(0)\n\ts_barrier" ::: "memory")

union FragAB {
  short4v s;
  __hip_bfloat162 h2[2];
};
union Frag8 {
  short8v s8;
  short4v s4[2];
};

__device__ inline short4v pack_bf16x4(float a, float b, float c, float d) {
  FragAB u;
  u.h2[0] = __float22bfloat162_rn(make_float2(a, b));
  u.h2[1] = __float22bfloat162_rn(make_float2(c, d));
  return u.s;
}

// every branch __has_builtin-guarded: the HOST pass must never see a branch
// whose builtin it can't resolve (falls through to never-executed asm).
__device__ inline float4v mfma_bf16(short4v a, short4v b, float4v c) {
#if __has_builtin(__builtin_amdgcn_mfma_f32_16x16x16bf16_1k)
  return __builtin_amdgcn_mfma_f32_16x16x16bf16_1k(a, b, c, 0, 0, 0);
#else
  float4v d;
  asm("v_mfma_f32_16x16x16_bf16 %0, %1, %2, %3"
      : "=v"(d) : "v"(a), "v"(b), "v"(c));
  return d;
#endif
}

__device__ inline float4v mfma_bf16_x32(short8v a, short8v b, float4v c) {
#if __has_builtin(__builtin_amdgcn_mfma_f32_16x16x32_bf16)
  return __builtin_amdgcn_mfma_f32_16x16x32_bf16(a, b, c, 0, 0, 0);
#else
  float4v d;
  asm("v_mfma_f32_16x16x32_bf16 %0, %1, %2, %3"
      : "=v"(d) : "v"(a), "v"(b), "v"(c));
  return d;
#endif
}

__global__ __launch_bounds__(64 * NW, 2)
void lrrnn_fused(const float* __restrict__ z0, const float* __restrict__ Adec,
                 const float* __restrict__ nmat, const float* __restrict__ mmat,
                 const float* __restrict__ hvec, const float* __restrict__ hzvec,
                 const float* __restrict__ Bobs, const float* __restrict__ Bias,
                 const int* __restrict__ Tptr, float* __restrict__ out)
{
  const int T    = Tptr[0];
  const int b    = blockIdx.x;
  const int tid  = threadIdx.x;
  const int wave = tid >> 6;
  const int lane = tid & 63;
  const int g    = lane >> 4;   // 0..3  (quad group)
  const int c    = lane & 15;   // 0..15 (column / row-in-tile)

  // single-buffered partials are race-free: wave0's reads complete before its
  // lgkmcnt(0)+barrier2; peers' next writes are post-barrier2.
  __shared__ float4v part[NW][64];
  __shared__ short4v zbuf[64];       // packed bf16 z broadcast (8 B/lane)

  // ---- one-time fragment preload (weights shared across blocks; L2-resident) ----
  // m A-frag (x16): A[row=c][k=4g+j] = m[(rowbase+c)*16 + 4g+j]
  // n A-frag (x32): slot j<4 -> n[c*1024 + rb+4g+j], j>=4 -> n[c*1024 + rb+16+4g+j-4]
  // negH C-frag: C[row=4g+r][col] = -h[rowbase + 4g+r]
  FragAB mf[ITER];
  Frag8  nf8[NH];
  float4v negH[ITER];
#pragma unroll
  for (int i = 0; i < ITER; ++i) {
    const int rowbase = wave * (16 * ITER) + i * 16;
    float4v mv = *(const float4v*)(mmat + (rowbase + c) * DZ + g * 4);
    mf[i].s = pack_bf16x4(mv[0], mv[1], mv[2], mv[3]);
    float4v hv = *(const float4v*)(hvec + rowbase + g * 4);
    negH[i][0] = -hv[0]; negH[i][1] = -hv[1];
    negH[i][2] = -hv[2]; negH[i][3] = -hv[3];
  }
#pragma unroll
  for (int i = 0; i < NH; ++i) {
    const int rb0 = wave * (16 * ITER) + (2 * i) * 16;
    float4v nv0 = *(const float4v*)(nmat + c * NN + rb0 + g * 4);
    float4v nv1 = *(const float4v*)(nmat + c * NN + rb0 + 16 + g * 4);
    nf8[i].s4[0] = pack_bf16x4(nv0[0], nv0[1], nv0[2], nv0[3]);
    nf8[i].s4[1] = pack_bf16x4(nv1[0], nv1[1], nv1[2], nv1[3]);
  }

  // decay / bias-z frags (C-layout rows = z = 4g+r); wave0 is the z owner
  const float4v Af  = *(const float4v*)(Adec + g * 4);
  const float4v hzf = *(const float4v*)(hzvec + g * 4);
  const float4v zerov = {0.f, 0.f, 0.f, 0.f};

  // ---- readout: wave w owns x-tile w (x in [16w, 16w+16)), NW==DX/16 ----
  // BobsT A-frag: A[row=x=c][k=z=4g+j] = Bobs[(4g+j)*128 + x]
  FragAB bobsF;
  float4v biasF;
  unsigned oof[4];
  {
    const int xb = wave * 16;
    bobsF.s = pack_bf16x4(Bobs[(4 * g + 0) * DX + xb + c],
                          Bobs[(4 * g + 1) * DX + xb + c],
                          Bobs[(4 * g + 2) * DX + xb + c],
                          Bobs[(4 * g + 3) * DX + xb + c]);
    biasF = *(const float4v*)(Bias + xb + g * 4);
#pragma unroll
    for (int rr = 0; rr < 4; ++rr) {
      const int x = xb + g * 4 + rr;
      oof[rr] = (unsigned)(b * DX + x) * (unsigned)T * KC + c;
    }
  }

  // z state: f32 master in wave0 only; all waves track packed bf16 zb
  float4v zf;
#pragma unroll
  for (int j = 0; j < 4; ++j)
    zf[j] = z0[b * DZ * KC + (g * 4 + j) * KC + c];
  FragAB zb;
  zb.s = pack_bf16x4(zf[0], zf[1], zf[2], zf[3]);

  // one recurrence step: batched phase A -> reduce -> broadcast. Updates zb.
  auto do_step = [&]() {
    // (1) all X-MFMAs, mutually independent given zb
    float4v xv[ITER];
#pragma unroll
    for (int i = 0; i < ITER; ++i)
      xv[i] = mfma_bf16(mf[i].s, zb.s, negH[i]);

    // (2) relu + pack into x32 B-frags (slot j<4 = tile 2i, j>=4 = tile 2i+1)
    Frag8 R8[NH];
#pragma unroll
    for (int i = 0; i < NH; ++i) {
      const float4v x0 = xv[2 * i], x1 = xv[2 * i + 1];
      R8[i].s4[0] = pack_bf16x4(fmaxf(x0[0], 0.f), fmaxf(x0[1], 0.f),
                                fmaxf(x0[2], 0.f), fmaxf(x0[3], 0.f));
      R8[i].s4[1] = pack_bf16x4(fmaxf(x1[0], 0.f), fmaxf(x1[1], 0.f),
                                fmaxf(x1[2], 0.f), fmaxf(x1[3], 0.f));
    }

    // (3) n@R: 4x mfma 16x16x32, 2 chains of depth 2; hz folded into wave0
    float4v a0 = mfma_bf16_x32(nf8[0].s8, R8[0].s8, (wave == 0) ? hzf : zerov);
    float4v a1 = mfma_bf16_x32(nf8[1].s8, R8[1].s8, zerov);
    a0 = mfma_bf16_x32(nf8[2].s8, R8[2].s8, a0);
    a1 = mfma_bf16_x32(nf8[3].s8, R8[3].s8, a1);
    const float4v zp = a0 + a1;

    part[wave][lane] = zp;
    BARRIER_LGKM();    // barrier 1: publish partials; NO vmcnt drain

    if (wave == 0) {
      const float4v p1 = part[1][lane];
      const float4v p2 = part[2][lane];
      const float4v p3 = part[3][lane];
      const float4v p4 = part[4][lane];
      const float4v p5 = part[5][lane];
      const float4v p6 = part[6][lane];
      const float4v p7 = part[7][lane];
      const float4v tot = ((zp + p1) + (p2 + p3)) + ((p4 + p5) + (p6 + p7));
#pragma unroll
      for (int j = 0; j < 4; ++j)
        zf[j] = fmaf(Af[j], zf[j], tot[j]);
      zb.s = pack_bf16x4(zf[0], zf[1], zf[2], zf[3]);
      zbuf[lane] = zb.s;
    }
    BARRIER_LGKM();    // barrier 2: publish zbuf (wave0's lgkmcnt covers it)

    if (wave != 0) zb.s = zbuf[lane];   // 8 B broadcast (2-way alias: free)
  };

  int t = 0;
  // ---- main: chunks of CH steps, readout batched from the register ring ----
  while (t + CH <= T) {
    short4v hist[CH];                 // compile-time-indexed -> stays in VGPRs
#pragma unroll
    for (int s = 0; s < CH; ++s) {
      do_step();
      hist[s] = zb.s;                 // zb = z_{t+s+1} -> out index t+s
    }
#pragma unroll
    for (int s = 0; s < CH; ++s) {
      float4v o = mfma_bf16(bobsF.s, hist[s], biasF);
      const unsigned tk = (unsigned)(t + s) * KC;
#pragma unroll
      for (int rr = 0; rr < 4; ++rr)
        out[oof[rr] + tk] = o[rr];
    }
    t += CH;
  }
  // ---- tail: per-step immediate readout (<=CH-1 steps) ----
  for (; t < T; ++t) {
    do_step();
    float4v o = mfma_bf16(bobsF.s, zb.s, biasF);
    const unsigned tk = (unsigned)t * KC;
#pragma unroll
    for (int rr = 0; rr < 4; ++rr)
      out[oof[rr] + tk] = o[rr];
  }
}

extern "C" void kernel_launch(void* const* d_in, const int* in_sizes, int n_in,
                              void* d_out, int out_size, void* d_ws, size_t ws_size,
                              hipStream_t stream) {
  const float* z0   = (const float*)d_in[0];
  const float* A    = (const float*)d_in[1];
  const float* nmat = (const float*)d_in[2];
  const float* mmat = (const float*)d_in[3];
  const float* h    = (const float*)d_in[4];
  const float* hz   = (const float*)d_in[5];
  const float* Bobs = (const float*)d_in[6];
  const float* Bias = (const float*)d_in[7];
  const int*   T    = (const int*)d_in[8];
  (void)in_sizes; (void)n_in; (void)out_size; (void)d_ws; (void)ws_size;
  lrrnn_fused<<<dim3(BB), dim3(64 * NW), 0, stream>>>(
      z0, A, nmat, mmat, h, hz, Bobs, Bias, T, (float*)d_out);
}